// Round 20
// baseline (230.447 us; speedup 1.0000x reference)
//
#include <hip/hip_runtime.h>
#include <hip/hip_fp16.h>
#include <math.h>

#define Bn 128
#define Nn 1000
#define Tn 50
#define En 32000
#define Rn 4
#define FSn 43
#define NSELn 500
#define NFtot (Nn * FSn)   // 43000

// ---------------------------------------------------------------------------
// Kernel 0: weight transpose prep.
//   w_s2T[t][oc] = w_s2[oc*48 + t]   (48 x 60)
//   w_m2T[t][oc] = w_m2[oc*30 + t]   (30 x 60)
// Makes each t-iteration's 60 conv2 weights CONSECUTIVE from a uniform base
// so the temporal kernel's scalar loads batch into s_load_dwordx16.
// ---------------------------------------------------------------------------
__global__ __launch_bounds__(256) void k_wprep(const float* __restrict__ w_s2,
                                               const float* __restrict__ w_m2,
                                               float* __restrict__ w_s2T,
                                               float* __restrict__ w_m2T)
{
    const int tid = threadIdx.x;
    for (int i = tid; i < 48 * 60; i += 256) {
        const int t  = i / 60;
        const int oc = i - t * 60;
        w_s2T[i] = w_s2[oc * 48 + t];
    }
    for (int i = tid; i < 30 * 60; i += 256) {
        const int t  = i / 60;
        const int oc = i - t * 60;
        w_m2T[i] = w_m2[oc * 30 + t];
    }
}

// ---------------------------------------------------------------------------
// Kernel 1: fused temporal features (loop structure FROZEN — 4/4 structural
// redesigns regressed). 512 thr = 8 waves, 64 nodes per block.
//   w0..w2: short conv t[w*16,(w+1)*16) + long-max third
//   w3..w7: mid conv t[(w-3)*6,(w-3)*6+6)
// Change vs R19: conv2 weights read from the transposed layout (w_s2T/w_m2T),
// 60 consecutive floats per t instead of 60 stride-192B scattered loads.
// Epilogue stores x as fp16.
// ---------------------------------------------------------------------------
__global__ __launch_bounds__(512) void k_temporal(
    const float* __restrict__ obs,
    const float* __restrict__ w_s1, const float* __restrict__ b_s1,
    const float* __restrict__ w_s2T, const float* __restrict__ b_s2,
    const float* __restrict__ w_m1, const float* __restrict__ b_m1,
    const float* __restrict__ w_m2T, const float* __restrict__ b_m2,
    __half* __restrict__ x)
{
    __shared__ float lds[3 * 64 * 51];

    const int b     = blockIdx.x;
    const int tile0 = blockIdx.y * 64;
    const int tid   = threadIdx.x;
    const int lane  = tid & 63;
    const int w     = __builtin_amdgcn_readfirstlane(tid >> 6);   // 0..7
    const int nrows = (Nn - tile0) < 64 ? (Nn - tile0) : 64;

    for (int c = 0; c < 3; ++c) {
        const float* srcp = obs + ((size_t)(b * 3 + c) * Nn + tile0) * Tn;
        for (int idx = tid; idx < nrows * Tn; idx += 512) {
            const int r = idx / Tn;
            const int t = idx - r * Tn;
            lds[(c * 64 + r) * 51 + t] = srcp[idx];
        }
    }
    __syncthreads();

    float acc[20];
    float mx0 = -1e30f, mx1 = -1e30f, mx2 = -1e30f;

    if (w < 3) {
        #pragma unroll
        for (int o = 0; o < 20; ++o) acc[o] = (w == 0) ? b_s2[o] : 0.f;

        const float s10 = b_s1[0], s11 = b_s1[1], s12 = b_s1[2];
        const int t0 = w * 16;

        #pragma unroll 1
        for (int t = t0; t < t0 + 16; ++t) {
            float ov[9];
            #pragma unroll
            for (int c = 0; c < 3; ++c)
                #pragma unroll
                for (int d = 0; d < 3; ++d)
                    ov[c * 3 + d] = lds[(c * 64 + lane) * 51 + t + d];

            float v0 = s10, v1 = s11, v2 = s12;
            #pragma unroll
            for (int c = 0; c < 3; ++c) {
                v0 += ov[c * 3 + 0] * w_s1[(0 * 3 + c) * 3 + 0]
                    + ov[c * 3 + 1] * w_s1[(0 * 3 + c) * 3 + 1]
                    + ov[c * 3 + 2] * w_s1[(0 * 3 + c) * 3 + 2];
                v1 += ov[c * 3 + 0] * w_s1[(1 * 3 + c) * 3 + 0]
                    + ov[c * 3 + 1] * w_s1[(1 * 3 + c) * 3 + 1]
                    + ov[c * 3 + 2] * w_s1[(1 * 3 + c) * 3 + 2];
                v2 += ov[c * 3 + 0] * w_s1[(2 * 3 + c) * 3 + 0]
                    + ov[c * 3 + 1] * w_s1[(2 * 3 + c) * 3 + 1]
                    + ov[c * 3 + 2] * w_s1[(2 * 3 + c) * 3 + 2];
            }
            v0 = fmaxf(v0, 0.f); v1 = fmaxf(v1, 0.f); v2 = fmaxf(v2, 0.f);
            const float* wst = w_s2T + t * 60;   // 60 consecutive weights
            #pragma unroll
            for (int o = 0; o < 20; ++o) {
                acc[o] += v0 * wst[o * 3 + 0]
                        + v1 * wst[o * 3 + 1]
                        + v2 * wst[o * 3 + 2];
            }
        }

        const int rb0 = (0 * 64 + lane) * 51;
        const int rb1 = (1 * 64 + lane) * 51;
        const int rb2 = (2 * 64 + lane) * 51;
        const int l0 = (w == 0) ? 0 : (w == 1) ? 17 : 34;
        const int l1 = (w == 0) ? 17 : (w == 1) ? 34 : 50;
        #pragma unroll 1
        for (int t = l0; t < l1; ++t) {
            mx0 = fmaxf(mx0, lds[rb0 + t]);
            mx1 = fmaxf(mx1, lds[rb1 + t]);
            mx2 = fmaxf(mx2, lds[rb2 + t]);
        }
    } else {
        #pragma unroll
        for (int o = 0; o < 20; ++o) acc[o] = (w == 3) ? b_m2[o] : 0.f;

        const float m10 = b_m1[0], m11 = b_m1[1], m12 = b_m1[2];
        const int t0 = (w - 3) * 6;

        #pragma unroll 1
        for (int t = t0; t < t0 + 6; ++t) {
            float v0 = m10, v1 = m11, v2 = m12;
            #pragma unroll
            for (int c = 0; c < 3; ++c) {
                const int base = (c * 64 + lane) * 51 + t;
                float p0 = 0.f, p1 = 0.f, p2 = 0.f;
                #pragma unroll
                for (int d = 0; d < 21; ++d) {
                    const float ov = lds[base + d];
                    p0 += ov * w_m1[(0 * 3 + c) * 21 + d];
                    p1 += ov * w_m1[(1 * 3 + c) * 21 + d];
                    p2 += ov * w_m1[(2 * 3 + c) * 21 + d];
                }
                v0 += p0; v1 += p1; v2 += p2;
            }
            v0 = fmaxf(v0, 0.f); v1 = fmaxf(v1, 0.f); v2 = fmaxf(v2, 0.f);
            const float* wmt = w_m2T + t * 60;   // 60 consecutive weights
            #pragma unroll
            for (int o = 0; o < 20; ++o) {
                acc[o] += v0 * wmt[o * 3 + 0]
                        + v1 * wmt[o * 3 + 1]
                        + v2 * wmt[o * 3 + 2];
            }
        }
    }

    __syncthreads();
    if (w == 1 || w == 2) {
        float* r = lds + (w - 1) * 1472 + lane;
        #pragma unroll
        for (int o = 0; o < 20; ++o) r[o * 64] = acc[o];
        r[20 * 64] = mx0;
        r[21 * 64] = mx1;
        r[22 * 64] = mx2;
    } else if (w >= 4) {
        float* r = lds + 2944 + (w - 4) * 1280 + lane;
        #pragma unroll
        for (int o = 0; o < 20; ++o) r[o * 64] = acc[o];
    }
    __syncthreads();

    if (lane < nrows) {
        __half* xp = x + ((size_t)b * Nn + tile0 + lane) * FSn;
        if (w == 0) {
            #pragma unroll
            for (int o = 0; o < 20; ++o) {
                const int a = o * 64 + lane;
                xp[o] = __float2half(fmaxf(acc[o] + lds[a] + lds[1472 + a], 0.f));
            }
            {
                const int a0 = 20 * 64 + lane, a1 = 21 * 64 + lane, a2 = 22 * 64 + lane;
                xp[40] = __float2half(fmaxf(fmaxf(mx0, fmaxf(lds[a0], lds[1472 + a0])), 0.f));
                xp[41] = __float2half(fmaxf(fmaxf(mx1, fmaxf(lds[a1], lds[1472 + a1])), 0.f));
                xp[42] = __float2half(fmaxf(fmaxf(mx2, fmaxf(lds[a2], lds[1472 + a2])), 0.f));
            }
        } else if (w == 3) {
            #pragma unroll
            for (int o = 0; o < 20; ++o) {
                const int a = 2944 + o * 64 + lane;
                xp[20 + o] = __float2half(fmaxf(acc[o] + lds[a] + lds[a + 1280]
                                                + lds[a + 2560] + lds[a + 3840], 0.f));
            }
        }
    }
}

// ---------------------------------------------------------------------------
// Transpose: x[b][nf] (fp16) -> xT[nf][b] (fp16)
// ---------------------------------------------------------------------------
__global__ __launch_bounds__(256) void k_transpose(const __half* __restrict__ x,
                                                   __half* __restrict__ xT)
{
    __shared__ __half tile[64][132];
    const int c0  = blockIdx.x * 64;
    const int tid = threadIdx.x;

    const int j  = tid & 63;
    const int bs = tid >> 6;
    for (int bb = bs; bb < Bn; bb += 4) {
        int c = c0 + j;
        if (c < NFtot) tile[j][bb] = x[(size_t)bb * NFtot + c];
    }
    __syncthreads();

    const int b  = tid & 127;
    for (int jj = (tid >> 7); jj < 64; jj += 2) {
        int c = c0 + jj;
        if (c < NFtot) xT[(size_t)c * Bn + b] = tile[jj][b];
    }
}

// ---------------------------------------------------------------------------
// CSR build (count/scan/fill; cnt+pos zeroed by hipMemsetAsync).
// ---------------------------------------------------------------------------
__global__ void k_count(const int* __restrict__ ei, const int* __restrict__ et,
                        int* __restrict__ cnt)
{
    int e = blockIdx.x * blockDim.x + threadIdx.x;
    if (e < En) {
        int dst = ei[En + e];
        atomicAdd(&cnt[dst * Rn + et[e]], 1);
    }
}

__global__ __launch_bounds__(1024) void k_scan(const int* __restrict__ cnt,
                                               int* __restrict__ off)
{
    __shared__ int sums[1024];
    int tid = threadIdx.x;
    int base = tid * 4;
    int c[4];
    int ts = 0;
    #pragma unroll
    for (int k = 0; k < 4; ++k) {
        int i = base + k;
        c[k] = (i < Nn * Rn) ? cnt[i] : 0;
        ts += c[k];
    }
    sums[tid] = ts;
    __syncthreads();
    for (int d = 1; d < 1024; d <<= 1) {
        int t = 0;
        if (tid >= d) t = sums[tid - d];
        __syncthreads();
        sums[tid] += t;
        __syncthreads();
    }
    int excl = sums[tid] - ts;
    #pragma unroll
    for (int k = 0; k < 4; ++k) {
        int i = base + k;
        off[i] = excl;
        excl += c[k];
    }
}

__global__ void k_fill(const int* __restrict__ ei, const int* __restrict__ et,
                       const int* __restrict__ off, int* __restrict__ pos,
                       int* __restrict__ csr)
{
    int e = blockIdx.x * blockDim.x + threadIdx.x;
    if (e < En) {
        int src = ei[e];
        int dst = ei[En + e];
        int seg = dst * Rn + et[e];
        int p = atomicAdd(&pos[seg], 1);
        csr[off[seg] + p] = src;
    }
}

// ---------------------------------------------------------------------------
// Kernel 2 (fused, b-half split — measured-best version): grid = 1000 =
// (sel i, batch half bh). 256 thr.
// ---------------------------------------------------------------------------
__global__ __launch_bounds__(256) void k_graph(
    const __half* __restrict__ xT,
    const float* __restrict__ w_rel, const float* __restrict__ w_root,
    const float* __restrict__ b_g,
    const float* __restrict__ w_fin, const float* __restrict__ b_fin,
    const float* __restrict__ la,
    const int* __restrict__ csr, const int* __restrict__ off,
    const int* __restrict__ cnt, const int* __restrict__ sel,
    float* __restrict__ logitT)
{
    __shared__ __align__(16) char smem[22016 + 2048 + 32];
    __half* ab    = (__half*)smem;                 // [4][43][64] halves
    int*    srcs  = (int*)(smem + 22016);          // [4][128]
    int*    scnt  = (int*)(smem + 22016 + 2048);   // [4] clamped
    int*    tcnt  = scnt + 4;                      // [4] true
    float*  red   = (float*)smem;                  // [44][64] aliases ab

    const int i   = blockIdx.x >> 1;
    const int bh  = blockIdx.x & 1;
    const int dst = sel[i];
    const int tid = threadIdx.x;

    {
        const int r = tid >> 6;
        const int c = cnt[dst * Rn + r];
        const int o = off[dst * Rn + r];
        if ((tid & 63) == 0) { tcnt[r] = c; scnt[r] = (c < 128) ? c : 128; }
        #pragma unroll
        for (int j = (tid & 63); j < 128; j += 64)
            if (j < c) srcs[r * 128 + j] = csr[o + j];
    }
    __syncthreads();

    {
        const int r  = tid >> 6;
        const int fc = (tid >> 4) & 3;
        const int b2 = tid & 15;
        const int nk = (fc < 3) ? 11 : 10;

        float4 acc[11];
        #pragma unroll
        for (int k = 0; k < 11; ++k) acc[k] = make_float4(0.f, 0.f, 0.f, 0.f);

        const int cc = scnt[r];
        const float2* xT2 = (const float2*)xT;
        for (int j = 0; j < cc; ++j) {
            const int src = srcs[r * 128 + j];
            const float2* base = xT2 + (size_t)src * (FSn * 32)
                               + (size_t)fc * 32 + bh * 16 + b2;
            #pragma unroll
            for (int k = 0; k < 11; ++k) {
                if (k < nk) {
                    float2 raw = base[(size_t)k * 128];
                    const __half2 h0 = ((const __half2*)&raw)[0];
                    const __half2 h1 = ((const __half2*)&raw)[1];
                    const float2 f0 = __half22float2(h0);
                    const float2 f1 = __half22float2(h1);
                    acc[k].x += f0.x; acc[k].y += f0.y;
                    acc[k].z += f1.x; acc[k].w += f1.y;
                }
            }
        }

        const int  tc  = tcnt[r];
        const float inv = (tc > 0) ? 1.f / (float)tc : 0.f;
        float2* ab2 = (float2*)ab;
        #pragma unroll
        for (int k = 0; k < 11; ++k) {
            if (k < nk) {
                const int f = fc + 4 * k;
                float2 st;
                ((__half2*)&st)[0] = __floats2half2_rn(acc[k].x * inv, acc[k].y * inv);
                ((__half2*)&st)[1] = __floats2half2_rn(acc[k].z * inv, acc[k].w * inv);
                ab2[(r * FSn + f) * 16 + b2] = st;
            }
        }
    }
    __syncthreads();

    const int fs = tid >> 6;
    const int bL = tid & 63;
    const int b  = bh * 64 + bL;
    const int f0 = fs * 11;
    const int nf = (fs == 3) ? 10 : 11;

    float a[5][11];
    #pragma unroll
    for (int rr = 0; rr < 4; ++rr) {
        #pragma unroll
        for (int k = 0; k < 11; ++k)
            a[rr][k] = (k < nf) ? __half2float(ab[(rr * FSn + f0 + k) * 64 + bL]) : 0.f;
    }
    {
        const __half* xp = xT + ((size_t)dst * FSn + f0) * Bn + b;
        #pragma unroll
        for (int k = 0; k < 11; ++k)
            a[4][k] = (k < nf) ? __half2float(xp[(size_t)k * Bn]) : 0.f;
    }

    float accg[FSn];
    #pragma unroll
    for (int g = 0; g < FSn; ++g) accg[g] = 0.f;
    float psum = 0.f;

    #pragma unroll
    for (int k = 0; k < 11; ++k) {
        if (k < nf) {
            const int f = f0 + k;
            #pragma unroll
            for (int rr = 0; rr < 5; ++rr) {
                const float av = a[rr][k];
                const float* wrow = (rr < 4)
                    ? (w_rel + ((size_t)rr * FSn + f) * FSn)
                    : (w_root + (size_t)f * FSn);
                #pragma unroll
                for (int g = 0; g < FSn; ++g) accg[g] += av * wrow[g];
            }
            psum += a[4][k] * w_fin[1 + f];
        }
    }

    __syncthreads();

    if (fs == 3) {
        #pragma unroll
        for (int g = 0; g < FSn; ++g) red[g * 64 + bL] = accg[g];
        red[FSn * 64 + bL] = psum;
    }
    __syncthreads();
    if (fs == 2) {
        #pragma unroll
        for (int g = 0; g < FSn; ++g) red[g * 64 + bL] += accg[g];
        red[FSn * 64 + bL] += psum;
    }
    __syncthreads();
    if (fs == 1) {
        #pragma unroll
        for (int g = 0; g < FSn; ++g) red[g * 64 + bL] += accg[g];
        red[FSn * 64 + bL] += psum;
    }
    __syncthreads();
    if (fs == 0) {
        float logit = b_fin[0] + w_fin[0] * la[(size_t)b * (NSELn + 1) + 1 + i]
                    + psum + red[FSn * 64 + bL];
        #pragma unroll
        for (int g = 0; g < FSn; ++g) {
            float v = accg[g] + red[g * 64 + bL] + b_g[g];
            v = (v > 0.f) ? v : 0.01f * v;
            logit += v * w_fin[44 + g];
        }
        logitT[(size_t)i * Bn + b] = logit;
    }
}

// ---------------------------------------------------------------------------
// Kernel 3: softmax over [0, logits(500)] per batch. Block per b.
// ---------------------------------------------------------------------------
__global__ __launch_bounds__(512) void k_softmax(const float* __restrict__ logitT,
                                                 float* __restrict__ out)
{
    __shared__ float red[512];
    const int b   = blockIdx.x;
    const int tid = threadIdx.x;

    const float l = (tid < NSELn) ? logitT[(size_t)tid * Bn + b] : -1e30f;
    red[tid] = l;
    __syncthreads();
    for (int s = 256; s > 0; s >>= 1) {
        if (tid < s) red[tid] = fmaxf(red[tid], red[tid + s]);
        __syncthreads();
    }
    const float m = fmaxf(red[0], 0.f);
    __syncthreads();

    const float e = (tid < NSELn) ? expf(l - m) : 0.f;
    red[tid] = e;
    __syncthreads();
    for (int s = 256; s > 0; s >>= 1) {
        if (tid < s) red[tid] += red[tid + s];
        __syncthreads();
    }
    const float e0  = expf(-m);
    const float inv = 1.f / (red[0] + e0);

    if (tid == 0) out[(size_t)b * (NSELn + 1)] = e0 * inv;
    if (tid < NSELn) out[(size_t)b * (NSELn + 1) + 1 + tid] = e * inv;
}

// ---------------------------------------------------------------------------
extern "C" void kernel_launch(void* const* d_in, const int* in_sizes, int n_in,
                              void* d_out, int out_size, void* d_ws, size_t ws_size,
                              hipStream_t stream)
{
    const float* obs    = (const float*)d_in[0];
    const float* la     = (const float*)d_in[1];
    const float* w_s1   = (const float*)d_in[2];
    const float* b_s1   = (const float*)d_in[3];
    const float* w_s2   = (const float*)d_in[4];
    const float* b_s2   = (const float*)d_in[5];
    const float* w_m1   = (const float*)d_in[6];
    const float* b_m1   = (const float*)d_in[7];
    const float* w_m2   = (const float*)d_in[8];
    const float* b_m2   = (const float*)d_in[9];
    const float* w_rel  = (const float*)d_in[10];
    const float* w_root = (const float*)d_in[11];
    const float* b_g    = (const float*)d_in[12];
    const float* w_fin  = (const float*)d_in[13];
    const float* b_fin  = (const float*)d_in[14];
    const int*   ei     = (const int*)d_in[15];
    const int*   et     = (const int*)d_in[16];
    const int*   sel    = (const int*)d_in[17];
    float*       out    = (float*)d_out;

    // workspace (bytes):
    //   x    : half, 11,008,000 B at 0
    //   xTh  : half, 11,008,000 B at 11,008,000
    //   cnt|pos (adjacent, one memset), off, csr, logitT, w_s2T|w_m2T
    char* wsb     = (char*)d_ws;
    __half* x     = (__half*)wsb;
    __half* xTh   = (__half*)(wsb + 11008000);
    int*   cnt    = (int*)(wsb + 22016000);
    int*   pos    = cnt + 4096;
    int*   offb   = pos + 4096;
    int*   csr    = offb + 4096;
    float* logitT = (float*)(csr + 32000);
    float* w_s2T  = logitT + NSELn * Bn;   // 2880 floats
    float* w_m2T  = w_s2T + 2880;          // 1800 floats

    hipMemsetAsync(cnt, 0, 2 * 4096 * sizeof(int), stream);   // cnt + pos
    hipLaunchKernelGGL(k_wprep, dim3(1), dim3(256), 0, stream, w_s2, w_m2, w_s2T, w_m2T);
    hipLaunchKernelGGL(k_count, dim3((En + 255) / 256), dim3(256), 0, stream, ei, et, cnt);
    hipLaunchKernelGGL(k_scan,  dim3(1),   dim3(1024), 0, stream, cnt, offb);
    hipLaunchKernelGGL(k_fill,  dim3((En + 255) / 256), dim3(256), 0, stream, ei, et, offb, pos, csr);

    hipLaunchKernelGGL(k_temporal, dim3(Bn, (Nn + 63) / 64), dim3(512), 0, stream,
                       obs, w_s1, b_s1, w_s2T, b_s2, w_m1, b_m1, w_m2T, b_m2, x);

    hipLaunchKernelGGL(k_transpose, dim3((NFtot + 63) / 64), dim3(256), 0, stream, x, xTh);

    hipLaunchKernelGGL(k_graph, dim3(NSELn * 2), dim3(256), 0, stream,
                       xTh, w_rel, w_root, b_g, w_fin, b_fin, la,
                       csr, offb, cnt, sel, logitT);

    hipLaunchKernelGGL(k_softmax, dim3(Bn), dim3(512), 0, stream, logitT, out);
}

// Round 21
// 226.866 us; speedup vs baseline: 1.0158x; 1.0158x over previous
//
#include <hip/hip_runtime.h>
#include <hip/hip_fp16.h>
#include <math.h>

#define Bn 128
#define Nn 1000
#define Tn 50
#define En 32000
#define Rn 4
#define FSn 43
#define NSELn 500
#define NFtot (Nn * FSn)   // 43000

// ---------------------------------------------------------------------------
// Kernel CSR-1 (+weight prep): edge count via global atomics; block 0 also
// transposes the conv2 weights (w_s2T[t][60], w_m2T[t][60]) so each
// t-iteration's 60 weights are consecutive (batched s_load in k_temporal).
// Folded here to avoid a separate tiny-kernel launch (R20: wprep launch ate
// the 4.7us temporal win).
// ---------------------------------------------------------------------------
__global__ void k_count(const int* __restrict__ ei, const int* __restrict__ et,
                        int* __restrict__ cnt,
                        const float* __restrict__ w_s2,
                        const float* __restrict__ w_m2,
                        float* __restrict__ w_s2T,
                        float* __restrict__ w_m2T)
{
    int e = blockIdx.x * blockDim.x + threadIdx.x;
    if (e < En) {
        int dst = ei[En + e];
        atomicAdd(&cnt[dst * Rn + et[e]], 1);
    }
    if (blockIdx.x == 0) {
        const int tid = threadIdx.x;
        for (int i = tid; i < 48 * 60; i += 256) {
            const int t  = i / 60;
            const int oc = i - t * 60;
            w_s2T[i] = w_s2[oc * 48 + t];
        }
        for (int i = tid; i < 30 * 60; i += 256) {
            const int t  = i / 60;
            const int oc = i - t * 60;
            w_m2T[i] = w_m2[oc * 30 + t];
        }
    }
}

// ---------------------------------------------------------------------------
// Kernel 1: fused temporal features (loop structure FROZEN). 512 thr =
// 8 waves, 64 nodes per block.
//   w0..w2: short conv t[w*16,(w+1)*16) + long-max third
//   w3..w7: mid conv t[(w-3)*6,(w-3)*6+6)
// conv2 weights from transposed layout (60 consecutive floats per t);
// epilogue stores x as fp16.
// ---------------------------------------------------------------------------
__global__ __launch_bounds__(512) void k_temporal(
    const float* __restrict__ obs,
    const float* __restrict__ w_s1, const float* __restrict__ b_s1,
    const float* __restrict__ w_s2T, const float* __restrict__ b_s2,
    const float* __restrict__ w_m1, const float* __restrict__ b_m1,
    const float* __restrict__ w_m2T, const float* __restrict__ b_m2,
    __half* __restrict__ x)
{
    __shared__ float lds[3 * 64 * 51];

    const int b     = blockIdx.x;
    const int tile0 = blockIdx.y * 64;
    const int tid   = threadIdx.x;
    const int lane  = tid & 63;
    const int w     = __builtin_amdgcn_readfirstlane(tid >> 6);   // 0..7
    const int nrows = (Nn - tile0) < 64 ? (Nn - tile0) : 64;

    for (int c = 0; c < 3; ++c) {
        const float* srcp = obs + ((size_t)(b * 3 + c) * Nn + tile0) * Tn;
        for (int idx = tid; idx < nrows * Tn; idx += 512) {
            const int r = idx / Tn;
            const int t = idx - r * Tn;
            lds[(c * 64 + r) * 51 + t] = srcp[idx];
        }
    }
    __syncthreads();

    float acc[20];
    float mx0 = -1e30f, mx1 = -1e30f, mx2 = -1e30f;

    if (w < 3) {
        #pragma unroll
        for (int o = 0; o < 20; ++o) acc[o] = (w == 0) ? b_s2[o] : 0.f;

        const float s10 = b_s1[0], s11 = b_s1[1], s12 = b_s1[2];
        const int t0 = w * 16;

        #pragma unroll 1
        for (int t = t0; t < t0 + 16; ++t) {
            float ov[9];
            #pragma unroll
            for (int c = 0; c < 3; ++c)
                #pragma unroll
                for (int d = 0; d < 3; ++d)
                    ov[c * 3 + d] = lds[(c * 64 + lane) * 51 + t + d];

            float v0 = s10, v1 = s11, v2 = s12;
            #pragma unroll
            for (int c = 0; c < 3; ++c) {
                v0 += ov[c * 3 + 0] * w_s1[(0 * 3 + c) * 3 + 0]
                    + ov[c * 3 + 1] * w_s1[(0 * 3 + c) * 3 + 1]
                    + ov[c * 3 + 2] * w_s1[(0 * 3 + c) * 3 + 2];
                v1 += ov[c * 3 + 0] * w_s1[(1 * 3 + c) * 3 + 0]
                    + ov[c * 3 + 1] * w_s1[(1 * 3 + c) * 3 + 1]
                    + ov[c * 3 + 2] * w_s1[(1 * 3 + c) * 3 + 2];
                v2 += ov[c * 3 + 0] * w_s1[(2 * 3 + c) * 3 + 0]
                    + ov[c * 3 + 1] * w_s1[(2 * 3 + c) * 3 + 1]
                    + ov[c * 3 + 2] * w_s1[(2 * 3 + c) * 3 + 2];
            }
            v0 = fmaxf(v0, 0.f); v1 = fmaxf(v1, 0.f); v2 = fmaxf(v2, 0.f);
            const float* wst = w_s2T + t * 60;
            #pragma unroll
            for (int o = 0; o < 20; ++o) {
                acc[o] += v0 * wst[o * 3 + 0]
                        + v1 * wst[o * 3 + 1]
                        + v2 * wst[o * 3 + 2];
            }
        }

        const int rb0 = (0 * 64 + lane) * 51;
        const int rb1 = (1 * 64 + lane) * 51;
        const int rb2 = (2 * 64 + lane) * 51;
        const int l0 = (w == 0) ? 0 : (w == 1) ? 17 : 34;
        const int l1 = (w == 0) ? 17 : (w == 1) ? 34 : 50;
        #pragma unroll 1
        for (int t = l0; t < l1; ++t) {
            mx0 = fmaxf(mx0, lds[rb0 + t]);
            mx1 = fmaxf(mx1, lds[rb1 + t]);
            mx2 = fmaxf(mx2, lds[rb2 + t]);
        }
    } else {
        #pragma unroll
        for (int o = 0; o < 20; ++o) acc[o] = (w == 3) ? b_m2[o] : 0.f;

        const float m10 = b_m1[0], m11 = b_m1[1], m12 = b_m1[2];
        const int t0 = (w - 3) * 6;

        #pragma unroll 1
        for (int t = t0; t < t0 + 6; ++t) {
            float v0 = m10, v1 = m11, v2 = m12;
            #pragma unroll
            for (int c = 0; c < 3; ++c) {
                const int base = (c * 64 + lane) * 51 + t;
                float p0 = 0.f, p1 = 0.f, p2 = 0.f;
                #pragma unroll
                for (int d = 0; d < 21; ++d) {
                    const float ov = lds[base + d];
                    p0 += ov * w_m1[(0 * 3 + c) * 21 + d];
                    p1 += ov * w_m1[(1 * 3 + c) * 21 + d];
                    p2 += ov * w_m1[(2 * 3 + c) * 21 + d];
                }
                v0 += p0; v1 += p1; v2 += p2;
            }
            v0 = fmaxf(v0, 0.f); v1 = fmaxf(v1, 0.f); v2 = fmaxf(v2, 0.f);
            const float* wmt = w_m2T + t * 60;
            #pragma unroll
            for (int o = 0; o < 20; ++o) {
                acc[o] += v0 * wmt[o * 3 + 0]
                        + v1 * wmt[o * 3 + 1]
                        + v2 * wmt[o * 3 + 2];
            }
        }
    }

    __syncthreads();
    if (w == 1 || w == 2) {
        float* r = lds + (w - 1) * 1472 + lane;
        #pragma unroll
        for (int o = 0; o < 20; ++o) r[o * 64] = acc[o];
        r[20 * 64] = mx0;
        r[21 * 64] = mx1;
        r[22 * 64] = mx2;
    } else if (w >= 4) {
        float* r = lds + 2944 + (w - 4) * 1280 + lane;
        #pragma unroll
        for (int o = 0; o < 20; ++o) r[o * 64] = acc[o];
    }
    __syncthreads();

    if (lane < nrows) {
        __half* xp = x + ((size_t)b * Nn + tile0 + lane) * FSn;
        if (w == 0) {
            #pragma unroll
            for (int o = 0; o < 20; ++o) {
                const int a = o * 64 + lane;
                xp[o] = __float2half(fmaxf(acc[o] + lds[a] + lds[1472 + a], 0.f));
            }
            {
                const int a0 = 20 * 64 + lane, a1 = 21 * 64 + lane, a2 = 22 * 64 + lane;
                xp[40] = __float2half(fmaxf(fmaxf(mx0, fmaxf(lds[a0], lds[1472 + a0])), 0.f));
                xp[41] = __float2half(fmaxf(fmaxf(mx1, fmaxf(lds[a1], lds[1472 + a1])), 0.f));
                xp[42] = __float2half(fmaxf(fmaxf(mx2, fmaxf(lds[a2], lds[1472 + a2])), 0.f));
            }
        } else if (w == 3) {
            #pragma unroll
            for (int o = 0; o < 20; ++o) {
                const int a = 2944 + o * 64 + lane;
                xp[20 + o] = __float2half(fmaxf(acc[o] + lds[a] + lds[a + 1280]
                                                + lds[a + 2560] + lds[a + 3840], 0.f));
            }
        }
    }
}

// ---------------------------------------------------------------------------
// Transpose: x[b][nf] (fp16) -> xT[nf][b] (fp16)
// ---------------------------------------------------------------------------
__global__ __launch_bounds__(256) void k_transpose(const __half* __restrict__ x,
                                                   __half* __restrict__ xT)
{
    __shared__ __half tile[64][132];
    const int c0  = blockIdx.x * 64;
    const int tid = threadIdx.x;

    const int j  = tid & 63;
    const int bs = tid >> 6;
    for (int bb = bs; bb < Bn; bb += 4) {
        int c = c0 + j;
        if (c < NFtot) tile[j][bb] = x[(size_t)bb * NFtot + c];
    }
    __syncthreads();

    const int b  = tid & 127;
    for (int jj = (tid >> 7); jj < 64; jj += 2) {
        int c = c0 + jj;
        if (c < NFtot) xT[(size_t)c * Bn + b] = tile[jj][b];
    }
}

// ---------------------------------------------------------------------------
// CSR scan/fill
// ---------------------------------------------------------------------------
__global__ __launch_bounds__(1024) void k_scan(const int* __restrict__ cnt,
                                               int* __restrict__ off)
{
    __shared__ int sums[1024];
    int tid = threadIdx.x;
    int base = tid * 4;
    int c[4];
    int ts = 0;
    #pragma unroll
    for (int k = 0; k < 4; ++k) {
        int i = base + k;
        c[k] = (i < Nn * Rn) ? cnt[i] : 0;
        ts += c[k];
    }
    sums[tid] = ts;
    __syncthreads();
    for (int d = 1; d < 1024; d <<= 1) {
        int t = 0;
        if (tid >= d) t = sums[tid - d];
        __syncthreads();
        sums[tid] += t;
        __syncthreads();
    }
    int excl = sums[tid] - ts;
    #pragma unroll
    for (int k = 0; k < 4; ++k) {
        int i = base + k;
        off[i] = excl;
        excl += c[k];
    }
}

__global__ void k_fill(const int* __restrict__ ei, const int* __restrict__ et,
                       const int* __restrict__ off, int* __restrict__ pos,
                       int* __restrict__ csr)
{
    int e = blockIdx.x * blockDim.x + threadIdx.x;
    if (e < En) {
        int src = ei[e];
        int dst = ei[En + e];
        int seg = dst * Rn + et[e];
        int p = atomicAdd(&pos[seg], 1);
        csr[off[seg] + p] = src;
    }
}

// ---------------------------------------------------------------------------
// Kernel 2 (fused, b-half split): grid = 1000 = (sel i, batch half bh).
// 256 thr.
// ---------------------------------------------------------------------------
__global__ __launch_bounds__(256) void k_graph(
    const __half* __restrict__ xT,
    const float* __restrict__ w_rel, const float* __restrict__ w_root,
    const float* __restrict__ b_g,
    const float* __restrict__ w_fin, const float* __restrict__ b_fin,
    const float* __restrict__ la,
    const int* __restrict__ csr, const int* __restrict__ off,
    const int* __restrict__ cnt, const int* __restrict__ sel,
    float* __restrict__ logitT)
{
    __shared__ __align__(16) char smem[22016 + 2048 + 32];
    __half* ab    = (__half*)smem;                 // [4][43][64] halves
    int*    srcs  = (int*)(smem + 22016);          // [4][128]
    int*    scnt  = (int*)(smem + 22016 + 2048);   // [4] clamped
    int*    tcnt  = scnt + 4;                      // [4] true
    float*  red   = (float*)smem;                  // [44][64] aliases ab

    const int i   = blockIdx.x >> 1;
    const int bh  = blockIdx.x & 1;
    const int dst = sel[i];
    const int tid = threadIdx.x;

    {
        const int r = tid >> 6;
        const int c = cnt[dst * Rn + r];
        const int o = off[dst * Rn + r];
        if ((tid & 63) == 0) { tcnt[r] = c; scnt[r] = (c < 128) ? c : 128; }
        #pragma unroll
        for (int j = (tid & 63); j < 128; j += 64)
            if (j < c) srcs[r * 128 + j] = csr[o + j];
    }
    __syncthreads();

    {
        const int r  = tid >> 6;
        const int fc = (tid >> 4) & 3;
        const int b2 = tid & 15;
        const int nk = (fc < 3) ? 11 : 10;

        float4 acc[11];
        #pragma unroll
        for (int k = 0; k < 11; ++k) acc[k] = make_float4(0.f, 0.f, 0.f, 0.f);

        const int cc = scnt[r];
        const float2* xT2 = (const float2*)xT;
        for (int j = 0; j < cc; ++j) {
            const int src = srcs[r * 128 + j];
            const float2* base = xT2 + (size_t)src * (FSn * 32)
                               + (size_t)fc * 32 + bh * 16 + b2;
            #pragma unroll
            for (int k = 0; k < 11; ++k) {
                if (k < nk) {
                    float2 raw = base[(size_t)k * 128];
                    const __half2 h0 = ((const __half2*)&raw)[0];
                    const __half2 h1 = ((const __half2*)&raw)[1];
                    const float2 f0 = __half22float2(h0);
                    const float2 f1 = __half22float2(h1);
                    acc[k].x += f0.x; acc[k].y += f0.y;
                    acc[k].z += f1.x; acc[k].w += f1.y;
                }
            }
        }

        const int  tc  = tcnt[r];
        const float inv = (tc > 0) ? 1.f / (float)tc : 0.f;
        float2* ab2 = (float2*)ab;
        #pragma unroll
        for (int k = 0; k < 11; ++k) {
            if (k < nk) {
                const int f = fc + 4 * k;
                float2 st;
                ((__half2*)&st)[0] = __floats2half2_rn(acc[k].x * inv, acc[k].y * inv);
                ((__half2*)&st)[1] = __floats2half2_rn(acc[k].z * inv, acc[k].w * inv);
                ab2[(r * FSn + f) * 16 + b2] = st;
            }
        }
    }
    __syncthreads();

    const int fs = tid >> 6;
    const int bL = tid & 63;
    const int b  = bh * 64 + bL;
    const int f0 = fs * 11;
    const int nf = (fs == 3) ? 10 : 11;

    float a[5][11];
    #pragma unroll
    for (int rr = 0; rr < 4; ++rr) {
        #pragma unroll
        for (int k = 0; k < 11; ++k)
            a[rr][k] = (k < nf) ? __half2float(ab[(rr * FSn + f0 + k) * 64 + bL]) : 0.f;
    }
    {
        const __half* xp = xT + ((size_t)dst * FSn + f0) * Bn + b;
        #pragma unroll
        for (int k = 0; k < 11; ++k)
            a[4][k] = (k < nf) ? __half2float(xp[(size_t)k * Bn]) : 0.f;
    }

    float accg[FSn];
    #pragma unroll
    for (int g = 0; g < FSn; ++g) accg[g] = 0.f;
    float psum = 0.f;

    #pragma unroll
    for (int k = 0; k < 11; ++k) {
        if (k < nf) {
            const int f = f0 + k;
            #pragma unroll
            for (int rr = 0; rr < 5; ++rr) {
                const float av = a[rr][k];
                const float* wrow = (rr < 4)
                    ? (w_rel + ((size_t)rr * FSn + f) * FSn)
                    : (w_root + (size_t)f * FSn);
                #pragma unroll
                for (int g = 0; g < FSn; ++g) accg[g] += av * wrow[g];
            }
            psum += a[4][k] * w_fin[1 + f];
        }
    }

    __syncthreads();

    if (fs == 3) {
        #pragma unroll
        for (int g = 0; g < FSn; ++g) red[g * 64 + bL] = accg[g];
        red[FSn * 64 + bL] = psum;
    }
    __syncthreads();
    if (fs == 2) {
        #pragma unroll
        for (int g = 0; g < FSn; ++g) red[g * 64 + bL] += accg[g];
        red[FSn * 64 + bL] += psum;
    }
    __syncthreads();
    if (fs == 1) {
        #pragma unroll
        for (int g = 0; g < FSn; ++g) red[g * 64 + bL] += accg[g];
        red[FSn * 64 + bL] += psum;
    }
    __syncthreads();
    if (fs == 0) {
        float logit = b_fin[0] + w_fin[0] * la[(size_t)b * (NSELn + 1) + 1 + i]
                    + psum + red[FSn * 64 + bL];
        #pragma unroll
        for (int g = 0; g < FSn; ++g) {
            float v = accg[g] + red[g * 64 + bL] + b_g[g];
            v = (v > 0.f) ? v : 0.01f * v;
            logit += v * w_fin[44 + g];
        }
        logitT[(size_t)i * Bn + b] = logit;
    }
}

// ---------------------------------------------------------------------------
// Kernel 3: softmax over [0, logits(500)] per batch. Block per b.
// ---------------------------------------------------------------------------
__global__ __launch_bounds__(512) void k_softmax(const float* __restrict__ logitT,
                                                 float* __restrict__ out)
{
    __shared__ float red[512];
    const int b   = blockIdx.x;
    const int tid = threadIdx.x;

    const float l = (tid < NSELn) ? logitT[(size_t)tid * Bn + b] : -1e30f;
    red[tid] = l;
    __syncthreads();
    for (int s = 256; s > 0; s >>= 1) {
        if (tid < s) red[tid] = fmaxf(red[tid], red[tid + s]);
        __syncthreads();
    }
    const float m = fmaxf(red[0], 0.f);
    __syncthreads();

    const float e = (tid < NSELn) ? expf(l - m) : 0.f;
    red[tid] = e;
    __syncthreads();
    for (int s = 256; s > 0; s >>= 1) {
        if (tid < s) red[tid] += red[tid + s];
        __syncthreads();
    }
    const float e0  = expf(-m);
    const float inv = 1.f / (red[0] + e0);

    if (tid == 0) out[(size_t)b * (NSELn + 1)] = e0 * inv;
    if (tid < NSELn) out[(size_t)b * (NSELn + 1) + 1 + tid] = e * inv;
}

// ---------------------------------------------------------------------------
extern "C" void kernel_launch(void* const* d_in, const int* in_sizes, int n_in,
                              void* d_out, int out_size, void* d_ws, size_t ws_size,
                              hipStream_t stream)
{
    const float* obs    = (const float*)d_in[0];
    const float* la     = (const float*)d_in[1];
    const float* w_s1   = (const float*)d_in[2];
    const float* b_s1   = (const float*)d_in[3];
    const float* w_s2   = (const float*)d_in[4];
    const float* b_s2   = (const float*)d_in[5];
    const float* w_m1   = (const float*)d_in[6];
    const float* b_m1   = (const float*)d_in[7];
    const float* w_m2   = (const float*)d_in[8];
    const float* b_m2   = (const float*)d_in[9];
    const float* w_rel  = (const float*)d_in[10];
    const float* w_root = (const float*)d_in[11];
    const float* b_g    = (const float*)d_in[12];
    const float* w_fin  = (const float*)d_in[13];
    const float* b_fin  = (const float*)d_in[14];
    const int*   ei     = (const int*)d_in[15];
    const int*   et     = (const int*)d_in[16];
    const int*   sel    = (const int*)d_in[17];
    float*       out    = (float*)d_out;

    // workspace (bytes):
    //   x    : half, 11,008,000 B at 0
    //   xTh  : half, 11,008,000 B at 11,008,000
    //   cnt|pos (adjacent, one memset), off, csr, logitT, w_s2T|w_m2T
    char* wsb     = (char*)d_ws;
    __half* x     = (__half*)wsb;
    __half* xTh   = (__half*)(wsb + 11008000);
    int*   cnt    = (int*)(wsb + 22016000);
    int*   pos    = cnt + 4096;
    int*   offb   = pos + 4096;
    int*   csr    = offb + 4096;
    float* logitT = (float*)(csr + 32000);
    float* w_s2T  = logitT + NSELn * Bn;   // 2880 floats
    float* w_m2T  = w_s2T + 2880;          // 1800 floats

    hipMemsetAsync(cnt, 0, 2 * 4096 * sizeof(int), stream);   // cnt + pos
    hipLaunchKernelGGL(k_count, dim3((En + 255) / 256), dim3(256), 0, stream,
                       ei, et, cnt, w_s2, w_m2, w_s2T, w_m2T);
    hipLaunchKernelGGL(k_scan,  dim3(1),   dim3(1024), 0, stream, cnt, offb);
    hipLaunchKernelGGL(k_fill,  dim3((En + 255) / 256), dim3(256), 0, stream, ei, et, offb, pos, csr);

    hipLaunchKernelGGL(k_temporal, dim3(Bn, (Nn + 63) / 64), dim3(512), 0, stream,
                       obs, w_s1, b_s1, w_s2T, b_s2, w_m1, b_m1, w_m2T, b_m2, x);

    hipLaunchKernelGGL(k_transpose, dim3((NFtot + 63) / 64), dim3(256), 0, stream, x, xTh);

    hipLaunchKernelGGL(k_graph, dim3(NSELn * 2), dim3(256), 0, stream,
                       xTh, w_rel, w_root, b_g, w_fin, b_fin, la,
                       csr, offb, cnt, sel, logitT);

    hipLaunchKernelGGL(k_softmax, dim3(Bn), dim3(512), 0, stream, logitT, out);
}